// Round 7
// baseline (332.046 us; speedup 1.0000x reference)
//
#include <hip/hip_runtime.h>
#include <stdint.h>

typedef __attribute__((ext_vector_type(4))) float f32x4;
typedef __attribute__((ext_vector_type(8))) short bf16x8;

#define MFMA_BF16 __builtin_amdgcn_mfma_f32_16x16x32_bf16

__device__ __forceinline__ unsigned short f2bf(float f) {
  union { float f; uint32_t u; } a; a.f = f;
  uint32_t u = a.u;
  uint32_t r = (u + 0x7FFFu + ((u >> 16) & 1u)) >> 16;
  return (unsigned short)r;
}

// Pack [x | h] -> bf16 A[4096][4096] row-major (K = IN(2048) then H(2048))
__global__ void pack_a_kernel(const float4* __restrict__ x, const float4* __restrict__ hh,
                              ushort4* __restrict__ A) {
  const int total = 4096 * 1024;
  for (int q = blockIdx.x * blockDim.x + threadIdx.x; q < total; q += gridDim.x * blockDim.x) {
    int row = q >> 10, cq = q & 1023;
    float4 v = (cq < 512) ? x[row * 512 + cq] : hh[row * 512 + (cq - 512)];
    ushort4 o; o.x = f2bf(v.x); o.y = f2bf(v.y); o.z = f2bf(v.z); o.w = f2bf(v.w);
    A[q] = o;
  }
}

// Pack 8 weight mats -> bf16 Wp[8192][4096].
// Packed row p: bn=p>>8, r=p&255; half=r>>7, wn=(r>>5)&3, glow=(r>>4)&1, hlow=r&15
//   gate g = half*2+glow ; hcol H = bn*64 + wn*16 + hlow
__global__ void pack_w_kernel(const float* __restrict__ Wii, const float* __restrict__ Wif,
                              const float* __restrict__ Wig, const float* __restrict__ Wio,
                              const float* __restrict__ Whi, const float* __restrict__ Whf,
                              const float* __restrict__ Whg, const float* __restrict__ Who,
                              ushort4* __restrict__ Wp) {
  const int total = 8192 * 1024;
  for (int q = blockIdx.x * blockDim.x + threadIdx.x; q < total; q += gridDim.x * blockDim.x) {
    int p = q >> 10, kq = q & 1023;
    int r = p & 255;
    int g = ((r >> 7) << 1) | ((r >> 4) & 1);
    int H = ((p >> 8) << 6) | (((r >> 5) & 3) << 4) | (r & 15);
    const float* src;
    if (kq < 512) src = (g == 0) ? Wii : (g == 1) ? Wif : (g == 2) ? Wig : Wio;
    else          src = (g == 0) ? Whi : (g == 1) ? Whf : (g == 2) ? Whg : Who;
    const float4 v = *(const float4*)&src[(size_t)H * 2048 + ((kq & 511) << 2)];
    ushort4 o; o.x = f2bf(v.x); o.y = f2bf(v.y); o.z = f2bf(v.z); o.w = f2bf(v.w);
    Wp[q] = o;
  }
}

// 256x256 tile, BK=32, 8 waves (2Mx4N), per-wave 128x64.
// 4-deep LDS ring (4 x 32 KB), stage T+3 during T, counted vmcnt(8) - NEVER
// drains in steady state. One barrier/tile, free-drift compute inside tile.
// Pair-interleaved LDS layout: (row r, chunk c) -> (r>>1)*128B + (r&1)*64B
// + (c ^ ((r>>1)&3))*16B  => conflict-free reads AND linear DMA writes.
#define GLD(srcp, dstE)                                                         \
  __builtin_amdgcn_global_load_lds(                                             \
      (const __attribute__((address_space(1))) void*)(srcp),                    \
      (__attribute__((address_space(3))) void*)(&smem[dstE]), 16, 0, 0)

#define STAGE(t_)                                                               \
  {                                                                             \
    const int rr_ = ((t_) & 3) << 14;                                           \
    const size_t kO_ = (size_t)(t_) * 32;                                       \
    GLD(aS + kO_, rr_ + dA);                                                    \
    GLD(aS + 524288 + kO_, rr_ + dA + 4096);                                    \
    GLD(bS + kO_, rr_ + dB);                                                    \
    GLD(bS + 524288 + kO_, rr_ + dB + 4096);                                    \
  }

__global__ __launch_bounds__(512, 2)
void lstm_gemm_kernel(const ushort* __restrict__ A, const ushort* __restrict__ Wp,
                      const float* __restrict__ c,
                      const float* __restrict__ bii, const float* __restrict__ bif_,
                      const float* __restrict__ big_, const float* __restrict__ bio_,
                      const float* __restrict__ bhi, const float* __restrict__ bhf,
                      const float* __restrict__ bhg, const float* __restrict__ bho,
                      float* __restrict__ out) {
  __shared__ ushort smem[65536];  // 4 ring bufs x (A 256x32 + B 256x32) = 128 KiB
  const int tid = threadIdx.x;
  const int lane = tid & 63, w = tid >> 6;
  const int wm = w >> 2, wn = w & 3;

  // bn-major XCD mapping: XCD x owns bn in [x*4, x*4+4) x all 16 bm.
  const int bid = blockIdx.x;
  const int xcd = bid & 7, qq = bid >> 3;
  const int bn = (xcd << 2) | (qq >> 4);
  const int bm = qq & 15;

  const int laneRow = lane & 15, lane16 = lane >> 4;
  // Read-side: swizzled chunk slot (uniform for A and B frags)
  const int chunkSwz = lane16 ^ ((laneRow >> 1) & 3);
  const int rdCommon = (laneRow >> 1) * 64 + (laneRow & 1) * 32 + chunkSwz * 8;
  const int aRB = wm * 2048 + rdCommon;            // + ring + miq*4096 + m*512
  const int bRB = 8192 + wn * 1024 + rdCommon;     // + ring + niq*4096 + n*512

  // Write-side: DMA lane l -> LDS byte l*16 => local row 2*(l>>3)+((l>>2)&1),
  // slot l&3 holding logical chunk (l&3)^((l>>3)&3)  (inverse of read swizzle).
  const int lrow = 2 * (lane >> 3) + ((lane >> 2) & 1);
  const int schunk = (lane & 3) ^ ((lane >> 3) & 3);
  const ushort* aS = A + (size_t)(bm * 256 + 16 * w + lrow) * 4096 + schunk * 8;
  const ushort* bS = Wp + (size_t)(bn * 256 + 16 * w + lrow) * 4096 + schunk * 8;
  const int dA = w * 512;          // + ring (+4096 for rows 128..255)
  const int dB = 8192 + w * 512;

  f32x4 acc[8][4];
#pragma unroll
  for (int i = 0; i < 8; i++)
#pragma unroll
    for (int j = 0; j < 4; j++) acc[i][j] = (f32x4){0.f, 0.f, 0.f, 0.f};

  // Prologue: stage tiles 0,1,2 (12 loads/wave), wait oldest 4 (tile 0).
  STAGE(0); STAGE(1); STAGE(2);
  asm volatile("s_waitcnt vmcnt(8)" ::: "memory");
  __builtin_amdgcn_s_barrier();
  __builtin_amdgcn_sched_barrier(0);

#pragma unroll 1
  for (int T = 0; T < 128; ++T) {
    const int ring = (T & 3) << 14;
    if (T < 125) STAGE(T + 3);

    bf16x8 bf[4], af0[4], af1[4];
#pragma unroll
    for (int ni = 0; ni < 4; ++ni)
      bf[ni] = *(const bf16x8*)&smem[ring + bRB + (ni >> 1) * 4096 + (ni & 1) * 512];
#pragma unroll
    for (int m = 0; m < 4; ++m)
      af0[m] = *(const bf16x8*)&smem[ring + aRB + m * 512];
    __builtin_amdgcn_s_setprio(1);
#pragma unroll
    for (int m = 0; m < 4; ++m)
#pragma unroll
      for (int ni = 0; ni < 4; ++ni)
        acc[m][ni] = MFMA_BF16(af0[m], bf[ni], acc[m][ni], 0, 0, 0);
    __builtin_amdgcn_s_setprio(0);
#pragma unroll
    for (int m = 0; m < 4; ++m)
      af1[m] = *(const bf16x8*)&smem[ring + aRB + 4096 + m * 512];
    __builtin_amdgcn_s_setprio(1);
#pragma unroll
    for (int m = 0; m < 4; ++m)
#pragma unroll
      for (int ni = 0; ni < 4; ++ni)
        acc[4 + m][ni] = MFMA_BF16(af1[m], bf[ni], acc[4 + m][ni], 0, 0, 0);
    __builtin_amdgcn_s_setprio(0);

    // Counted wait: oldest outstanding batch = tile T+1's 4 loads.
    if (T < 125)       asm volatile("s_waitcnt vmcnt(8)" ::: "memory");
    else if (T == 125) asm volatile("s_waitcnt vmcnt(4)" ::: "memory");
    else if (T == 126) asm volatile("s_waitcnt vmcnt(0)" ::: "memory");
    if (T < 127) {
      __builtin_amdgcn_s_barrier();
      __builtin_amdgcn_sched_barrier(0);
    }
  }

  // Fused LSTM epilogue: acc[mi][gate][rr] register-local per (row, hcol).
  const int hcol = bn * 64 + wn * 16 + laneRow;
  const float bI = bii[hcol] + bhi[hcol];
  const float bF = bif_[hcol] + bhf[hcol];
  const float bG = big_[hcol] + bhg[hcol];
  const float bO = bio_[hcol] + bho[hcol];
#pragma unroll
  for (int mi = 0; mi < 8; ++mi) {
    const int rowBase = bm * 256 + (mi >> 2) * 128 + wm * 64 + (mi & 3) * 16 + lane16 * 4;
#pragma unroll
    for (int rr = 0; rr < 4; ++rr) {
      const int row = rowBase + rr;
      const float ii = acc[mi][0][rr] + bI;
      const float ff = acc[mi][1][rr] + bF;
      const float gg = acc[mi][2][rr] + bG;
      const float oo = acc[mi][3][rr] + bO;
      const float iv = 1.f / (1.f + __expf(-ii));
      const float fv = 1.f / (1.f + __expf(-ff));
      const float gv = tanhf(gg);
      const float ov = 1.f / (1.f + __expf(-oo));
      const float cv = c[(size_t)row * 2048 + hcol];
      const float cn = fv * cv + iv * gv;
      const float hn = ov * tanhf(cn);
      out[(size_t)row * 2048 + hcol] = hn;
      out[(size_t)8388608 + (size_t)row * 2048 + hcol] = cn;
    }
  }
}

extern "C" void kernel_launch(void* const* d_in, const int* in_sizes, int n_in,
                              void* d_out, int out_size, void* d_ws, size_t ws_size,
                              hipStream_t stream) {
  const float* x = (const float*)d_in[0];
  const float* h = (const float*)d_in[1];
  const float* c = (const float*)d_in[2];
  const float* Wii = (const float*)d_in[3];  const float* bii = (const float*)d_in[4];
  const float* Wif = (const float*)d_in[5];  const float* bif_ = (const float*)d_in[6];
  const float* Wig = (const float*)d_in[7];  const float* big_ = (const float*)d_in[8];
  const float* Wio = (const float*)d_in[9];  const float* bio_ = (const float*)d_in[10];
  const float* Whi = (const float*)d_in[11]; const float* bhi = (const float*)d_in[12];
  const float* Whf = (const float*)d_in[13]; const float* bhf = (const float*)d_in[14];
  const float* Whg = (const float*)d_in[15]; const float* bhg = (const float*)d_in[16];
  const float* Who = (const float*)d_in[17]; const float* bho = (const float*)d_in[18];

  ushort* Abf = (ushort*)d_ws;                    // 4096*4096 bf16
  ushort* Wpk = Abf + (size_t)4096 * 4096;        // 8192*4096 bf16
  float* out = (float*)d_out;

  pack_a_kernel<<<2048, 256, 0, stream>>>((const float4*)x, (const float4*)h, (ushort4*)Abf);
  pack_w_kernel<<<2048, 256, 0, stream>>>(Wii, Wif, Wig, Wio, Whi, Whf, Whg, Who, (ushort4*)Wpk);
  lstm_gemm_kernel<<<512, 512, 0, stream>>>(Abf, Wpk, c,
                                            bii, bif_, big_, bio_, bhi, bhf, bhg, bho, out);
}